// Round 1
// baseline (42.922 us; speedup 1.0000x reference)
//
#include <hip/hip_runtime.h>

// Problem constants (from reference): B=32, C=3, W=256, H=256
#define PLANE 65536                 // W*H
#define NPIX  (32 * PLANE)          // B*W*H = 2,097,152
// scale = WEIGHT * 0.5 / NPIX  (the /2 of the loss and the mean)
#define SCALE (0.5f / 2097152.0f)

__global__ __launch_bounds__(256) void loss_gau_kernel(
    const float* __restrict__ x_mean,    // [B,3,W,H]
    const float* __restrict__ x_var,     // [B,3,3,W,H] (symmetric in (c1,c2))
    const float* __restrict__ n_sigma,   // [B,1,1,W,H]
    const float* __restrict__ target,    // [B,3,W,H]
    float* __restrict__ out)             // [1]
{
    const int tid = blockIdx.x * blockDim.x + threadIdx.x;
    const int p   = tid << 2;           // 4 pixels per thread, exact cover
    const int b   = p >> 16;            // p / PLANE
    const int r   = p & (PLANE - 1);    // offset within plane (multiple of 4)

    const float* xm = x_mean  + (size_t)b * 3 * PLANE + r;
    const float* xv = x_var   + (size_t)b * 9 * PLANE + r;
    const float* ns = n_sigma + (size_t)b * PLANE     + r;
    const float* tg = target  + (size_t)b * 3 * PLANE + r;

    // Upper triangle of the 3x3 covariance (planes 0,1,2,4,5,8)
    const float4 v00 = *(const float4*)(xv + 0 * PLANE);
    const float4 v01 = *(const float4*)(xv + 1 * PLANE);
    const float4 v02 = *(const float4*)(xv + 2 * PLANE);
    const float4 v11 = *(const float4*)(xv + 4 * PLANE);
    const float4 v12 = *(const float4*)(xv + 5 * PLANE);
    const float4 v22 = *(const float4*)(xv + 8 * PLANE);
    const float4 m0  = *(const float4*)(xm + 0 * PLANE);
    const float4 m1  = *(const float4*)(xm + 1 * PLANE);
    const float4 m2  = *(const float4*)(xm + 2 * PLANE);
    const float4 t0  = *(const float4*)(tg + 0 * PLANE);
    const float4 t1  = *(const float4*)(tg + 1 * PLANE);
    const float4 t2  = *(const float4*)(tg + 2 * PLANE);
    const float4 sg  = *(const float4*)(ns);

    float acc = 0.0f;
#pragma unroll
    for (int i = 0; i < 4; ++i) {
        const float s  = ((const float*)&sg)[i];
        const float s2 = s * s;
        const float a  = ((const float*)&v00)[i] + s2;
        const float bb = ((const float*)&v01)[i];
        const float c  = ((const float*)&v02)[i];
        const float d  = ((const float*)&v11)[i] + s2;
        const float e  = ((const float*)&v12)[i];
        const float f  = ((const float*)&v22)[i] + s2;

        const float r0 = ((const float*)&t0)[i] - ((const float*)&m0)[i];
        const float r1 = ((const float*)&t1)[i] - ((const float*)&m1)[i];
        const float r2 = ((const float*)&t2)[i] - ((const float*)&m2)[i];

        // cofactors (adjugate of symmetric 3x3)
        const float A00 = d * f - e * e;
        const float A01 = c * e - bb * f;
        const float A02 = bb * e - c * d;
        const float A11 = a * f - c * c;
        const float A12 = bb * c - a * e;
        const float A22 = a * d - bb * bb;

        const float det = a * A00 + bb * A01 + c * A02;   // > 0 (PSD + 0.1I + s2*I)

        const float quad = r0 * r0 * A00 + r1 * r1 * A11 + r2 * r2 * A22
                         + 2.0f * (r0 * r1 * A01 + r0 * r2 * A02 + r1 * r2 * A12);

        acc += quad / det + __logf(det);
    }

    // wave-64 butterfly reduce
#pragma unroll
    for (int off = 32; off > 0; off >>= 1)
        acc += __shfl_down(acc, off, 64);

    __shared__ float wsum[4];
    const int lane = threadIdx.x & 63;
    const int wid  = threadIdx.x >> 6;
    if (lane == 0) wsum[wid] = acc;
    __syncthreads();
    if (threadIdx.x == 0) {
        const float blocksum = wsum[0] + wsum[1] + wsum[2] + wsum[3];
        atomicAdd(out, blocksum * SCALE);
    }
}

extern "C" void kernel_launch(void* const* d_in, const int* in_sizes, int n_in,
                              void* d_out, int out_size, void* d_ws, size_t ws_size,
                              hipStream_t stream) {
    const float* x_mean  = (const float*)d_in[0];
    const float* x_var   = (const float*)d_in[1];
    const float* n_sigma = (const float*)d_in[2];
    const float* target  = (const float*)d_in[3];
    float* out = (float*)d_out;

    // d_out is poisoned (0xAA) once before timing and never re-poisoned;
    // we accumulate with atomics, so zero it every call (capture-safe).
    hipMemsetAsync(out, 0, sizeof(float), stream);

    // 2048 blocks * 256 threads * 4 pixels = 2,097,152 = NPIX exactly
    loss_gau_kernel<<<2048, 256, 0, stream>>>(x_mean, x_var, n_sigma, target, out);
}

// Round 2
// 23.918 us; speedup vs baseline: 1.7945x; 1.7945x over previous
//
#include <hip/hip_runtime.h>

// Problem constants (from reference): B=32, C=3, W=256, H=256
#define PLANE 65536                 // W*H
#define NPIX  (32 * PLANE)          // B*W*H = 2,097,152
#define NBLK  2048                  // NPIX / (256 threads * 4 px)
// scale = WEIGHT * mean * 0.5  (the /2 of the loss and the mean)
#define SCALE (0.5f / 2097152.0f)

__global__ __launch_bounds__(256) void loss_gau_kernel(
    const float* __restrict__ x_mean,    // [B,3,W,H]
    const float* __restrict__ x_var,     // [B,3,3,W,H] (symmetric in (c1,c2))
    const float* __restrict__ n_sigma,   // [B,1,1,W,H]
    const float* __restrict__ target,    // [B,3,W,H]
    float* __restrict__ partial)         // [NBLK]
{
    const int tid = blockIdx.x * blockDim.x + threadIdx.x;
    const int p   = tid << 2;           // 4 pixels per thread, exact cover
    const int b   = p >> 16;            // p / PLANE
    const int r   = p & (PLANE - 1);    // offset within plane (multiple of 4)

    const float* xm = x_mean  + (size_t)b * 3 * PLANE + r;
    const float* xv = x_var   + (size_t)b * 9 * PLANE + r;
    const float* ns = n_sigma + (size_t)b * PLANE     + r;
    const float* tg = target  + (size_t)b * 3 * PLANE + r;

    // Upper triangle of the 3x3 covariance (planes 0,1,2,4,5,8)
    const float4 v00 = *(const float4*)(xv + 0 * PLANE);
    const float4 v01 = *(const float4*)(xv + 1 * PLANE);
    const float4 v02 = *(const float4*)(xv + 2 * PLANE);
    const float4 v11 = *(const float4*)(xv + 4 * PLANE);
    const float4 v12 = *(const float4*)(xv + 5 * PLANE);
    const float4 v22 = *(const float4*)(xv + 8 * PLANE);
    const float4 m0  = *(const float4*)(xm + 0 * PLANE);
    const float4 m1  = *(const float4*)(xm + 1 * PLANE);
    const float4 m2  = *(const float4*)(xm + 2 * PLANE);
    const float4 t0  = *(const float4*)(tg + 0 * PLANE);
    const float4 t1  = *(const float4*)(tg + 1 * PLANE);
    const float4 t2  = *(const float4*)(tg + 2 * PLANE);
    const float4 sg  = *(const float4*)(ns);

    float acc = 0.0f;
#pragma unroll
    for (int i = 0; i < 4; ++i) {
        const float s  = ((const float*)&sg)[i];
        const float s2 = s * s;
        const float a  = ((const float*)&v00)[i] + s2;
        const float bb = ((const float*)&v01)[i];
        const float c  = ((const float*)&v02)[i];
        const float d  = ((const float*)&v11)[i] + s2;
        const float e  = ((const float*)&v12)[i];
        const float f  = ((const float*)&v22)[i] + s2;

        const float r0 = ((const float*)&t0)[i] - ((const float*)&m0)[i];
        const float r1 = ((const float*)&t1)[i] - ((const float*)&m1)[i];
        const float r2 = ((const float*)&t2)[i] - ((const float*)&m2)[i];

        // cofactors (adjugate of symmetric 3x3)
        const float A00 = d * f - e * e;
        const float A01 = c * e - bb * f;
        const float A02 = bb * e - c * d;
        const float A11 = a * f - c * c;
        const float A12 = bb * c - a * e;
        const float A22 = a * d - bb * bb;

        const float det = a * A00 + bb * A01 + c * A02;   // > 0 (PSD + 0.1I + s2*I)

        const float quad = r0 * r0 * A00 + r1 * r1 * A11 + r2 * r2 * A22
                         + 2.0f * (r0 * r1 * A01 + r0 * r2 * A02 + r1 * r2 * A12);

        acc += quad / det + __logf(det);
    }

    // wave-64 butterfly reduce
#pragma unroll
    for (int off = 32; off > 0; off >>= 1)
        acc += __shfl_down(acc, off, 64);

    __shared__ float wsum[4];
    const int lane = threadIdx.x & 63;
    const int wid  = threadIdx.x >> 6;
    if (lane == 0) wsum[wid] = acc;
    __syncthreads();
    if (threadIdx.x == 0)
        partial[blockIdx.x] = wsum[0] + wsum[1] + wsum[2] + wsum[3];
}

__global__ __launch_bounds__(256) void reduce_kernel(
    const float* __restrict__ partial,   // [NBLK]
    float* __restrict__ out)             // [1]
{
    const float4* p4 = (const float4*)partial;   // NBLK/4 = 512 float4
    float acc = 0.0f;
#pragma unroll
    for (int i = 0; i < 2; ++i) {
        const float4 v = p4[threadIdx.x + 256 * i];
        acc += (v.x + v.y) + (v.z + v.w);
    }
#pragma unroll
    for (int off = 32; off > 0; off >>= 1)
        acc += __shfl_down(acc, off, 64);

    __shared__ float wsum[4];
    const int lane = threadIdx.x & 63;
    const int wid  = threadIdx.x >> 6;
    if (lane == 0) wsum[wid] = acc;
    __syncthreads();
    if (threadIdx.x == 0)
        out[0] = (wsum[0] + wsum[1] + wsum[2] + wsum[3]) * SCALE;
}

extern "C" void kernel_launch(void* const* d_in, const int* in_sizes, int n_in,
                              void* d_out, int out_size, void* d_ws, size_t ws_size,
                              hipStream_t stream) {
    const float* x_mean  = (const float*)d_in[0];
    const float* x_var   = (const float*)d_in[1];
    const float* n_sigma = (const float*)d_in[2];
    const float* target  = (const float*)d_in[3];
    float* out     = (float*)d_out;
    float* partial = (float*)d_ws;   // NBLK floats = 8 KB scratch

    // 2048 blocks * 256 threads * 4 pixels = 2,097,152 = NPIX exactly.
    // Every partial[] slot is written each call -> no init needed, no atomics.
    loss_gau_kernel<<<NBLK, 256, 0, stream>>>(x_mean, x_var, n_sigma, target, partial);
    reduce_kernel<<<1, 256, 0, stream>>>(partial, out);
}

// Round 3
// 23.004 us; speedup vs baseline: 1.8658x; 1.0397x over previous
//
#include <hip/hip_runtime.h>

// Problem constants (from reference): B=32, C=3, W=256, H=256
#define PLANE 65536                 // W*H
#define NPIX  (32 * PLANE)          // B*W*H = 2,097,152
#define NBLK  1024                  // NPIX / (256 threads * 8 px)
// scale = WEIGHT * mean * 0.5  (the /2 of the loss and the mean)
#define SCALE (0.5f / 2097152.0f)

// Per-4-pixel closed-form: build symmetric 3x3, adjugate/det, quad + logdet.
__device__ __forceinline__ float pix4(
    float4 v00, float4 v01, float4 v02, float4 v11, float4 v12, float4 v22,
    float4 m0, float4 m1, float4 m2, float4 t0, float4 t1, float4 t2,
    float4 sg)
{
    float acc = 0.0f;
#pragma unroll
    for (int i = 0; i < 4; ++i) {
        const float s  = ((const float*)&sg)[i];
        const float s2 = s * s;
        const float a  = ((const float*)&v00)[i] + s2;
        const float bb = ((const float*)&v01)[i];
        const float c  = ((const float*)&v02)[i];
        const float d  = ((const float*)&v11)[i] + s2;
        const float e  = ((const float*)&v12)[i];
        const float f  = ((const float*)&v22)[i] + s2;

        const float r0 = ((const float*)&t0)[i] - ((const float*)&m0)[i];
        const float r1 = ((const float*)&t1)[i] - ((const float*)&m1)[i];
        const float r2 = ((const float*)&t2)[i] - ((const float*)&m2)[i];

        const float A00 = d * f - e * e;
        const float A01 = c * e - bb * f;
        const float A02 = bb * e - c * d;
        const float A11 = a * f - c * c;
        const float A12 = bb * c - a * e;
        const float A22 = a * d - bb * bb;

        const float det = a * A00 + bb * A01 + c * A02;   // > 0 (PSD + 0.1I + s2*I)

        const float quad = r0 * r0 * A00 + r1 * r1 * A11 + r2 * r2 * A22
                         + 2.0f * (r0 * r1 * A01 + r0 * r2 * A02 + r1 * r2 * A12);

        acc += quad / det + __logf(det);
    }
    return acc;
}

__global__ __launch_bounds__(256, 4) void loss_gau_kernel(
    const float* __restrict__ x_mean,    // [B,3,W,H]
    const float* __restrict__ x_var,     // [B,3,3,W,H] (symmetric in (c1,c2))
    const float* __restrict__ n_sigma,   // [B,1,1,W,H]
    const float* __restrict__ target,    // [B,3,W,H]
    float* __restrict__ partial)         // [NBLK]
{
    // Each block owns 2048 consecutive pixels of one image (32 blocks/plane).
    // Thread t handles two contiguous 4-px chunks 1024 px apart: both halves
    // are perfectly coalesced 16 B/lane streams. 26 loads issued before any
    // compute -> 2x the outstanding VMEM of the 4-px version.
    const int base = blockIdx.x << 11;               // *2048
    const int b    = base >> 16;                     // image index
    const int r0   = (base & (PLANE - 1)) + (threadIdx.x << 2);
    const int r1   = r0 + 1024;

    const float* xm = x_mean  + (size_t)b * 3 * PLANE;
    const float* xv = x_var   + (size_t)b * 9 * PLANE;
    const float* ns = n_sigma + (size_t)b * PLANE;
    const float* tg = target  + (size_t)b * 3 * PLANE;

    // segment A loads
    const float4 a_v00 = *(const float4*)(xv + 0 * PLANE + r0);
    const float4 a_v01 = *(const float4*)(xv + 1 * PLANE + r0);
    const float4 a_v02 = *(const float4*)(xv + 2 * PLANE + r0);
    const float4 a_v11 = *(const float4*)(xv + 4 * PLANE + r0);
    const float4 a_v12 = *(const float4*)(xv + 5 * PLANE + r0);
    const float4 a_v22 = *(const float4*)(xv + 8 * PLANE + r0);
    const float4 a_m0  = *(const float4*)(xm + 0 * PLANE + r0);
    const float4 a_m1  = *(const float4*)(xm + 1 * PLANE + r0);
    const float4 a_m2  = *(const float4*)(xm + 2 * PLANE + r0);
    const float4 a_t0  = *(const float4*)(tg + 0 * PLANE + r0);
    const float4 a_t1  = *(const float4*)(tg + 1 * PLANE + r0);
    const float4 a_t2  = *(const float4*)(tg + 2 * PLANE + r0);
    const float4 a_sg  = *(const float4*)(ns + r0);
    // segment B loads
    const float4 b_v00 = *(const float4*)(xv + 0 * PLANE + r1);
    const float4 b_v01 = *(const float4*)(xv + 1 * PLANE + r1);
    const float4 b_v02 = *(const float4*)(xv + 2 * PLANE + r1);
    const float4 b_v11 = *(const float4*)(xv + 4 * PLANE + r1);
    const float4 b_v12 = *(const float4*)(xv + 5 * PLANE + r1);
    const float4 b_v22 = *(const float4*)(xv + 8 * PLANE + r1);
    const float4 b_m0  = *(const float4*)(xm + 0 * PLANE + r1);
    const float4 b_m1  = *(const float4*)(xm + 1 * PLANE + r1);
    const float4 b_m2  = *(const float4*)(xm + 2 * PLANE + r1);
    const float4 b_t0  = *(const float4*)(tg + 0 * PLANE + r1);
    const float4 b_t1  = *(const float4*)(tg + 1 * PLANE + r1);
    const float4 b_t2  = *(const float4*)(tg + 2 * PLANE + r1);
    const float4 b_sg  = *(const float4*)(ns + r1);

    float acc = pix4(a_v00, a_v01, a_v02, a_v11, a_v12, a_v22,
                     a_m0, a_m1, a_m2, a_t0, a_t1, a_t2, a_sg)
              + pix4(b_v00, b_v01, b_v02, b_v11, b_v12, b_v22,
                     b_m0, b_m1, b_m2, b_t0, b_t1, b_t2, b_sg);

    // wave-64 butterfly reduce
#pragma unroll
    for (int off = 32; off > 0; off >>= 1)
        acc += __shfl_down(acc, off, 64);

    __shared__ float wsum[4];
    const int lane = threadIdx.x & 63;
    const int wid  = threadIdx.x >> 6;
    if (lane == 0) wsum[wid] = acc;
    __syncthreads();
    if (threadIdx.x == 0)
        partial[blockIdx.x] = wsum[0] + wsum[1] + wsum[2] + wsum[3];
}

__global__ __launch_bounds__(256) void reduce_kernel(
    const float* __restrict__ partial,   // [NBLK]
    float* __restrict__ out)             // [1]
{
    const float4* p4 = (const float4*)partial;   // NBLK/4 = 256 float4
    const float4 v = p4[threadIdx.x];
    float acc = (v.x + v.y) + (v.z + v.w);
#pragma unroll
    for (int off = 32; off > 0; off >>= 1)
        acc += __shfl_down(acc, off, 64);

    __shared__ float wsum[4];
    const int lane = threadIdx.x & 63;
    const int wid  = threadIdx.x >> 6;
    if (lane == 0) wsum[wid] = acc;
    __syncthreads();
    if (threadIdx.x == 0)
        out[0] = (wsum[0] + wsum[1] + wsum[2] + wsum[3]) * SCALE;
}

extern "C" void kernel_launch(void* const* d_in, const int* in_sizes, int n_in,
                              void* d_out, int out_size, void* d_ws, size_t ws_size,
                              hipStream_t stream) {
    const float* x_mean  = (const float*)d_in[0];
    const float* x_var   = (const float*)d_in[1];
    const float* n_sigma = (const float*)d_in[2];
    const float* target  = (const float*)d_in[3];
    float* out     = (float*)d_out;
    float* partial = (float*)d_ws;   // NBLK floats = 4 KB scratch

    // 1024 blocks * 256 threads * 8 pixels = 2,097,152 = NPIX exactly.
    // Every partial[] slot is written each call -> no init needed, no atomics.
    loss_gau_kernel<<<NBLK, 256, 0, stream>>>(x_mean, x_var, n_sigma, target, partial);
    reduce_kernel<<<1, 256, 0, stream>>>(partial, out);
}